// Round 10
// baseline (50.104 us; speedup 1.0000x reference)
//
#include <hip/hip_runtime.h>

#define NA 64
#define MOVE 4
#define OBS 5124
#define ROWS 80        // dyn inner row stride (elements)
#define NB 256
#define NTASK (NB * NA)   // 16384 (b,i) tasks
#define OUTC 20
#define WPB 4             // waves per block (1 task per wave)
#define NPART 16          // blocks per batch element

// ws layout: bf16x8 frag tables [0..191] (bf16x8 units), float [784..799] bvo,
// partials at float offset WS_PART: [4096 blocks][1024] floats (16.8 MB)
#define WS_WQ 0
#define WS_WK 64
#define WS_WV 128
#define WS_BVO 784
#define WS_PART 1024

typedef __attribute__((ext_vector_type(8))) short bf16x8;
typedef __attribute__((ext_vector_type(4))) float f32x4;

__device__ __forceinline__ short f2bf(float f) {
    __bf16 h = (__bf16)f;
    return __builtin_bit_cast(short, h);
}
__device__ __forceinline__ bf16x8 pack4(f32x4 v) {
    bf16x8 t;
    t[0] = f2bf(v[0]); t[1] = f2bf(v[1]); t[2] = f2bf(v[2]); t[3] = f2bf(v[3]);
    t[4] = 0; t[5] = 0; t[6] = 0; t[7] = 0;
    return t;
}
__device__ __forceinline__ bf16x8 pack8(f32x4 lo, f32x4 hi) {
    bf16x8 t;
    t[0] = f2bf(lo[0]); t[1] = f2bf(lo[1]); t[2] = f2bf(lo[2]); t[3] = f2bf(lo[3]);
    t[4] = f2bf(hi[0]); t[5] = f2bf(hi[1]); t[6] = f2bf(hi[2]); t[7] = f2bf(hi[3]);
    return t;
}
// dyn fragment: slots 0-3 = data, slot 4 = bias-activation (1.0 on g==0 lanes)
__device__ __forceinline__ bf16x8 dyfrag(f32x4 v, short s4) {
    bf16x8 t;
    t[0] = f2bf(v[0]); t[1] = f2bf(v[1]); t[2] = f2bf(v[2]); t[3] = f2bf(v[3]);
    t[4] = s4; t[5] = 0; t[6] = 0; t[7] = 0;
    return t;
}

__global__ __launch_bounds__(256) void prep_kernel(
    const float* __restrict__ Wq, const float* __restrict__ bq,
    const float* __restrict__ Wk, const float* __restrict__ bk,
    const float* __restrict__ Wv, const float* __restrict__ bv,
    const float* __restrict__ Wo, const float* __restrict__ bo,
    float* __restrict__ ws)
{
    __shared__ float sWvo[256];
    const float SC = 0.36067376022224085f;   // 0.25 * log2(e)
    int tid = threadIdx.x;
    {
        int e = tid >> 4, d = tid & 15;
        float acc = 0.f;
        #pragma unroll
        for (int c = 0; c < 16; ++c) acc += Wv[e * 16 + c] * Wo[c * 16 + d];
        sWvo[e * 16 + d] = acc;
    }
    __syncthreads();
    if (tid < 64) {
        int g = tid >> 4, c = tid & 15;
        bf16x8 q, k, v;
        #pragma unroll
        for (int r = 0; r < 4; ++r) {
            q[r] = f2bf(Wq[(4 * g + r) * 16 + c]);
            k[r] = f2bf(SC * Wk[(4 * g + r) * 16 + c]);
            v[r] = f2bf(sWvo[(4 * g + r) * 16 + c]);
            // bias in k-slot 16 (A-side k=16 <-> c==0, slot 4+r): D += bias[4g+r]*1
            q[4 + r] = (c == 0) ? f2bf(bq[4 * g + r]) : (short)0;
            k[4 + r] = (c == 0) ? f2bf(SC * bk[4 * g + r]) : (short)0;
            v[4 + r] = 0;
        }
        ((bf16x8*)ws)[WS_WQ + tid] = q;
        ((bf16x8*)ws)[WS_WK + tid] = k;
        ((bf16x8*)ws)[WS_WV + tid] = v;
    }
    if (tid < 16) {
        float bb = bo[tid];
        #pragma unroll
        for (int c = 0; c < 16; ++c) bb += bv[c] * Wo[c * 16 + tid];
        ws[WS_BVO + tid] = bb;
    }
}

// grid: NTASK/WPB = 4096 blocks of 256; wave w handles task idx = blockIdx*4 + w
__global__ __launch_bounds__(256, 8) void attn_kernel(
    const float* __restrict__ inp,
    const float* __restrict__ ws,
    float* __restrict__ out)
{
    __shared__ float sBuf[WPB * 1024];   // 16 KiB: dyn stage, then per-wave results

    const int tid  = threadIdx.x;
    const int lane = tid & 63;
    const int w    = tid >> 6;
    const int idx  = blockIdx.x * WPB + w;    // b*NA + i
    const int g    = lane >> 4;
    const int c    = lane & 15;
    float* chunk = sBuf + (w << 10);          // this wave's 64x16 fp32 tile

    // passthrough: out row head = inp row head
    if (lane == 0) {
        float4 mv = *(const float4*)(inp + (size_t)idx * OBS);
        *(float4*)(out + (size_t)idx * OUTC) = mv;
    }

    // ---- stage dyn tile into LDS: lane (g,c) covers rows 16i+c, elems 4g..4g+3 ----
    {
        const float* dynp = inp + (size_t)idx * OBS + MOVE + (size_t)c * ROWS + 4 * g;
        f32x4 t0 = *(const f32x4*)(dynp + 0 * 16 * ROWS);
        f32x4 t1 = *(const f32x4*)(dynp + 1 * 16 * ROWS);
        f32x4 t2 = *(const f32x4*)(dynp + 2 * 16 * ROWS);
        f32x4 t3 = *(const f32x4*)(dynp + 3 * 16 * ROWS);
        *(f32x4*)(chunk + (16 * 0 + c) * 16 + 4 * g) = t0;
        *(f32x4*)(chunk + (16 * 1 + c) * 16 + 4 * g) = t1;
        *(f32x4*)(chunk + (16 * 2 + c) * 16 + 4 * g) = t2;
        *(f32x4*)(chunk + (16 * 3 + c) * 16 + 4 * g) = t3;
    }

    const f32x4 zc = {0.f, 0.f, 0.f, 0.f};
    const short s4 = (g == 0) ? (short)0x3f80 : (short)0;   // bf16 1.0 bias activation
    const float4 bvo_r = *(const float4*)(ws + WS_BVO + 4 * g);

    // ---- three single-weight passes over the LDS tile (low register pressure) ----
    bf16x8 qb[4], kb[4], vb_lo, vb_hi;
    {
        const bf16x8 wq = ((const bf16x8*)ws)[WS_WQ + lane];
        #pragma unroll
        for (int i = 0; i < 4; ++i) {
            f32x4 d = *(const f32x4*)(chunk + i * 256 + c * 16 + 4 * g);
            qb[i] = pack4(__builtin_amdgcn_mfma_f32_16x16x32_bf16(wq, dyfrag(d, s4), zc, 0, 0, 0));
        }
    }
    {
        const bf16x8 wk = ((const bf16x8*)ws)[WS_WK + lane];
        #pragma unroll
        for (int i = 0; i < 4; ++i) {
            f32x4 d = *(const f32x4*)(chunk + i * 256 + c * 16 + 4 * g);
            kb[i] = pack4(__builtin_amdgcn_mfma_f32_16x16x32_bf16(wk, dyfrag(d, s4), zc, 0, 0, 0));
        }
    }
    {
        const bf16x8 wv = ((const bf16x8*)ws)[WS_WV + lane];
        f32x4 v0, v1, v2, v3;
        {
            f32x4 d = *(const f32x4*)(chunk + 0 * 256 + c * 16 + 4 * g);
            v0 = __builtin_amdgcn_mfma_f32_16x16x32_bf16(dyfrag(d, s4), wv, zc, 0, 0, 0);
            d = *(const f32x4*)(chunk + 1 * 256 + c * 16 + 4 * g);
            v1 = __builtin_amdgcn_mfma_f32_16x16x32_bf16(dyfrag(d, s4), wv, zc, 0, 0, 0);
            d = *(const f32x4*)(chunk + 2 * 256 + c * 16 + 4 * g);
            v2 = __builtin_amdgcn_mfma_f32_16x16x32_bf16(dyfrag(d, s4), wv, zc, 0, 0, 0);
            d = *(const f32x4*)(chunk + 3 * 256 + c * 16 + 4 * g);
            v3 = __builtin_amdgcn_mfma_f32_16x16x32_bf16(dyfrag(d, s4), wv, zc, 0, 0, 0);
        }
        vb_lo = pack8(v0, v1);
        vb_hi = pack8(v2, v3);
    }

    // ---- per t-tile j: S^T halves, streaming no-max softmax, packed PV ----
    #pragma unroll
    for (int j = 0; j < 4; ++j) {
        float part = 0.f;
        bf16x8 p_lo, p_hi;
        {
            f32x4 s0 = __builtin_amdgcn_mfma_f32_16x16x32_bf16(kb[0], qb[j], zc, 0, 0, 0);
            f32x4 s1 = __builtin_amdgcn_mfma_f32_16x16x32_bf16(kb[1], qb[j], zc, 0, 0, 0);
            #pragma unroll
            for (int r = 0; r < 4; ++r) {
                s0[r] = __builtin_amdgcn_exp2f(s0[r]); part += s0[r];
                s1[r] = __builtin_amdgcn_exp2f(s1[r]); part += s1[r];
            }
            p_lo = pack8(s0, s1);
        }
        {
            f32x4 s2 = __builtin_amdgcn_mfma_f32_16x16x32_bf16(kb[2], qb[j], zc, 0, 0, 0);
            f32x4 s3 = __builtin_amdgcn_mfma_f32_16x16x32_bf16(kb[3], qb[j], zc, 0, 0, 0);
            #pragma unroll
            for (int r = 0; r < 4; ++r) {
                s2[r] = __builtin_amdgcn_exp2f(s2[r]); part += s2[r];
                s3[r] = __builtin_amdgcn_exp2f(s3[r]); part += s3[r];
            }
            p_hi = pack8(s2, s3);
        }
        part += __shfl_xor(part, 16);
        part += __shfl_xor(part, 32);
        float inv = __builtin_amdgcn_rcpf(part);

        f32x4 ot;
        ot = __builtin_amdgcn_mfma_f32_16x16x32_bf16(vb_lo, p_lo, zc, 0, 0, 0);
        ot = __builtin_amdgcn_mfma_f32_16x16x32_bf16(vb_hi, p_hi, ot, 0, 0, 0);

        // normalize, +bvo, relu -> back into this wave's LDS chunk (dyn is dead)
        float4 st;
        st.x = fmaxf(fmaf(ot[0], inv, bvo_r.x), 0.f);
        st.y = fmaxf(fmaf(ot[1], inv, bvo_r.y), 0.f);
        st.z = fmaxf(fmaf(ot[2], inv, bvo_r.z), 0.f);
        st.w = fmaxf(fmaf(ot[3], inv, bvo_r.w), 0.f);
        *(float4*)(chunk + (16 * j + c) * 16 + 4 * g) = st;
    }

    __syncthreads();

    // ---- block reduce over 4 waves -> coalesced float4 partial per thread ----
    {
        int t = tid >> 2, dq = tid & 3;
        float4 st = make_float4(0.f, 0.f, 0.f, 0.f);
        #pragma unroll
        for (int ww = 0; ww < WPB; ++ww) {
            const float4 a = *(const float4*)(&sBuf[(ww << 10) + t * 16 + dq * 4]);
            st.x += a.x; st.y += a.y; st.z += a.z; st.w += a.w;
        }
        *(float4*)((float*)ws + WS_PART + (size_t)blockIdx.x * 1024 + t * 16 + dq * 4) = st;
    }
}

// grid: NB blocks; sums NPART partials per output element (accum region only)
__global__ __launch_bounds__(256) void reduce_kernel(
    const float* __restrict__ ws, float* __restrict__ out)
{
    const int b   = blockIdx.x;
    const int tid = threadIdx.x;
    const float* pb = ws + WS_PART + (size_t)b * (NPART * 1024);

    int e4 = tid * 4;                 // e = t*16 + d
    float4 s = make_float4(0.f, 0.f, 0.f, 0.f);
    #pragma unroll
    for (int p = 0; p < NPART; ++p) {
        const float4 a = *(const float4*)(pb + p * 1024 + e4);
        s.x += a.x; s.y += a.y; s.z += a.z; s.w += a.w;
    }
    int t = e4 >> 4, d = e4 & 15;
    *(float4*)(out + ((size_t)b * NA + t) * OUTC + MOVE + d) = s;
}

extern "C" void kernel_launch(void* const* d_in, const int* in_sizes, int n_in,
                              void* d_out, int out_size, void* d_ws, size_t ws_size,
                              hipStream_t stream) {
    const float* inp = (const float*)d_in[0];
    const float* Wq  = (const float*)d_in[1];
    const float* bq  = (const float*)d_in[2];
    const float* Wk  = (const float*)d_in[3];
    const float* bk  = (const float*)d_in[4];
    const float* Wv  = (const float*)d_in[5];
    const float* bv  = (const float*)d_in[6];
    const float* Wo  = (const float*)d_in[7];
    const float* bo  = (const float*)d_in[8];
    float* out = (float*)d_out;
    float* ws  = (float*)d_ws;

    hipLaunchKernelGGL(prep_kernel, dim3(1), dim3(256), 0, stream,
                       Wq, bq, Wk, bk, Wv, bv, Wo, bo, ws);
    hipLaunchKernelGGL(attn_kernel, dim3(NTASK / WPB), dim3(256), 0, stream, inp, ws, out);
    hipLaunchKernelGGL(reduce_kernel, dim3(NB), dim3(256), 0, stream, ws, out);
}

// Round 11
// 44.618 us; speedup vs baseline: 1.1230x; 1.1230x over previous
//
#include <hip/hip_runtime.h>

#define NA 64
#define MOVE 4
#define OBS 5124
#define ROWS 80        // dyn inner row stride (elements)
#define NB 256
#define NTASK (NB * NA)   // 16384 (b,i) tasks
#define OUTC 20
#define WPB 4             // waves per block (1 task per wave)
#define NPART 16          // blocks per batch element

// ws layout: bf16x8 frag tables [0..191] (bf16x8 units, biases folded in k-slot 16),
// partials at float offset WS_PART: [4096 blocks][1024] floats (16.8 MB)
#define WS_WQ 0
#define WS_WK 64
#define WS_WV 128
#define WS_PART 1024

typedef __attribute__((ext_vector_type(8))) short bf16x8;
typedef __attribute__((ext_vector_type(4))) float f32x4;

__device__ __forceinline__ short f2bf(float f) {
    __bf16 h = (__bf16)f;
    return __builtin_bit_cast(short, h);
}
__device__ __forceinline__ bf16x8 pack4(f32x4 v) {
    bf16x8 t;
    t[0] = f2bf(v[0]); t[1] = f2bf(v[1]); t[2] = f2bf(v[2]); t[3] = f2bf(v[3]);
    t[4] = 0; t[5] = 0; t[6] = 0; t[7] = 0;
    return t;
}
__device__ __forceinline__ bf16x8 pack8(f32x4 lo, f32x4 hi) {
    bf16x8 t;
    t[0] = f2bf(lo[0]); t[1] = f2bf(lo[1]); t[2] = f2bf(lo[2]); t[3] = f2bf(lo[3]);
    t[4] = f2bf(hi[0]); t[5] = f2bf(hi[1]); t[6] = f2bf(hi[2]); t[7] = f2bf(hi[3]);
    return t;
}
// dyn fragment: slots 0-3 = data, slot 4 = 1.0 on g==0 lanes (bias activation, k=16)
__device__ __forceinline__ bf16x8 dyfrag(f32x4 v, short s4) {
    bf16x8 t;
    t[0] = f2bf(v[0]); t[1] = f2bf(v[1]); t[2] = f2bf(v[2]); t[3] = f2bf(v[3]);
    t[4] = s4; t[5] = 0; t[6] = 0; t[7] = 0;
    return t;
}

__global__ __launch_bounds__(256) void prep_kernel(
    const float* __restrict__ Wq, const float* __restrict__ bq,
    const float* __restrict__ Wk, const float* __restrict__ bk,
    const float* __restrict__ Wv, const float* __restrict__ bv,
    const float* __restrict__ Wo, const float* __restrict__ bo,
    float* __restrict__ ws)
{
    __shared__ float sWvo[256];
    const float SC = 0.36067376022224085f;   // 0.25 * log2(e)
    int tid = threadIdx.x;
    {
        int e = tid >> 4, d = tid & 15;
        float acc = 0.f;
        #pragma unroll
        for (int c = 0; c < 16; ++c) acc += Wv[e * 16 + c] * Wo[c * 16 + d];
        sWvo[e * 16 + d] = acc;
    }
    __syncthreads();
    if (tid < 64) {
        int g = tid >> 4, c = tid & 15;
        bf16x8 q, k, v;
        #pragma unroll
        for (int r = 0; r < 4; ++r) {
            q[r] = f2bf(Wq[(4 * g + r) * 16 + c]);
            k[r] = f2bf(SC * Wk[(4 * g + r) * 16 + c]);
            v[r] = f2bf(sWvo[(4 * g + r) * 16 + c]);
        }
        // k=16 slot (g==0, slot 4) carries the bias row/col; zero-bias here so exact
        float bvo_c = bo[c];
        #pragma unroll
        for (int e = 0; e < 16; ++e) bvo_c += bv[e] * Wo[e * 16 + c];
        q[4] = (g == 0) ? f2bf(bq[c]) : (short)0;
        k[4] = (g == 0) ? f2bf(SC * bk[c]) : (short)0;
        v[4] = (g == 0) ? f2bf(bvo_c) : (short)0;
        q[5] = q[6] = q[7] = 0;
        k[5] = k[6] = k[7] = 0;
        v[5] = v[6] = v[7] = 0;
        ((bf16x8*)ws)[WS_WQ + tid] = q;
        ((bf16x8*)ws)[WS_WK + tid] = k;
        ((bf16x8*)ws)[WS_WV + tid] = v;
    }
}

// grid: NTASK/WPB = 4096 blocks of 256; wave w handles task idx = blockIdx*4 + w
__global__ __launch_bounds__(256, 8) void attn_kernel(
    const float* __restrict__ inp,
    const float* __restrict__ ws)
{
    __shared__ float sRed[WPB * 64 * OUTC];   // 20 KiB

    const int tid  = threadIdx.x;
    const int lane = tid & 63;
    const int w    = tid >> 6;
    const int idx  = blockIdx.x * WPB + w;    // b*NA + i
    const int g    = lane >> 4;
    const int c    = lane & 15;

    const bf16x8 wq = ((const bf16x8*)ws)[WS_WQ + lane];
    const bf16x8 wk = ((const bf16x8*)ws)[WS_WK + lane];
    const bf16x8 wv = ((const bf16x8*)ws)[WS_WV + lane];
    const short s4 = (g == 0) ? (short)0x3f80 : (short)0;   // bf16 1.0

    // dyn loads issued up-front (4 x dwordx4, stride 5120 B)
    const float* dynp = inp + (size_t)idx * OBS + MOVE + (size_t)c * ROWS + 4 * g;
    f32x4 f0 = *(const f32x4*)(dynp + 0 * 16 * ROWS);
    f32x4 f1 = *(const f32x4*)(dynp + 1 * 16 * ROWS);
    f32x4 f2 = *(const f32x4*)(dynp + 2 * 16 * ROWS);
    f32x4 f3 = *(const f32x4*)(dynp + 3 * 16 * ROWS);

    const f32x4 zc = {0.f, 0.f, 0.f, 0.f};

    // projections consumed per-i (dy fragments die early; biases via k=16 slot)
    bf16x8 qb[4], kb[4], vb_lo, vb_hi;
    {
        bf16x8 d0 = dyfrag(f0, s4);
        qb[0] = pack4(__builtin_amdgcn_mfma_f32_16x16x32_bf16(wq, d0, zc, 0, 0, 0));
        kb[0] = pack4(__builtin_amdgcn_mfma_f32_16x16x32_bf16(wk, d0, zc, 0, 0, 0));
        f32x4 v0 = __builtin_amdgcn_mfma_f32_16x16x32_bf16(d0, wv, zc, 0, 0, 0);
        bf16x8 d1 = dyfrag(f1, s4);
        qb[1] = pack4(__builtin_amdgcn_mfma_f32_16x16x32_bf16(wq, d1, zc, 0, 0, 0));
        kb[1] = pack4(__builtin_amdgcn_mfma_f32_16x16x32_bf16(wk, d1, zc, 0, 0, 0));
        f32x4 v1 = __builtin_amdgcn_mfma_f32_16x16x32_bf16(d1, wv, zc, 0, 0, 0);
        vb_lo = pack8(v0, v1);
        bf16x8 d2 = dyfrag(f2, s4);
        qb[2] = pack4(__builtin_amdgcn_mfma_f32_16x16x32_bf16(wq, d2, zc, 0, 0, 0));
        kb[2] = pack4(__builtin_amdgcn_mfma_f32_16x16x32_bf16(wk, d2, zc, 0, 0, 0));
        f32x4 v2 = __builtin_amdgcn_mfma_f32_16x16x32_bf16(d2, wv, zc, 0, 0, 0);
        bf16x8 d3 = dyfrag(f3, s4);
        qb[3] = pack4(__builtin_amdgcn_mfma_f32_16x16x32_bf16(wq, d3, zc, 0, 0, 0));
        kb[3] = pack4(__builtin_amdgcn_mfma_f32_16x16x32_bf16(wk, d3, zc, 0, 0, 0));
        f32x4 v3 = __builtin_amdgcn_mfma_f32_16x16x32_bf16(d3, wv, zc, 0, 0, 0);
        vb_hi = pack8(v2, v3);
    }

    // per t-tile j: S^T, streaming no-max softmax (exp2, scale folded), packed PV
    #pragma unroll
    for (int j = 0; j < 4; ++j) {
        f32x4 s0 = __builtin_amdgcn_mfma_f32_16x16x32_bf16(kb[0], qb[j], zc, 0, 0, 0);
        f32x4 s1 = __builtin_amdgcn_mfma_f32_16x16x32_bf16(kb[1], qb[j], zc, 0, 0, 0);
        f32x4 s2 = __builtin_amdgcn_mfma_f32_16x16x32_bf16(kb[2], qb[j], zc, 0, 0, 0);
        f32x4 s3 = __builtin_amdgcn_mfma_f32_16x16x32_bf16(kb[3], qb[j], zc, 0, 0, 0);

        float part = 0.f;
        #pragma unroll
        for (int r = 0; r < 4; ++r) {
            s0[r] = __builtin_amdgcn_exp2f(s0[r]); part += s0[r];
            s1[r] = __builtin_amdgcn_exp2f(s1[r]); part += s1[r];
            s2[r] = __builtin_amdgcn_exp2f(s2[r]); part += s2[r];
            s3[r] = __builtin_amdgcn_exp2f(s3[r]); part += s3[r];
        }
        part += __shfl_xor(part, 16);
        part += __shfl_xor(part, 32);
        float inv = __builtin_amdgcn_rcpf(part);

        bf16x8 p_lo = pack8(s0, s1);
        bf16x8 p_hi = pack8(s2, s3);

        f32x4 ot;
        ot = __builtin_amdgcn_mfma_f32_16x16x32_bf16(vb_lo, p_lo, zc, 0, 0, 0);
        ot = __builtin_amdgcn_mfma_f32_16x16x32_bf16(vb_hi, p_hi, ot, 0, 0, 0);

        // normalize + relu (bvo already folded into V'): stage to LDS
        float4 st;
        st.x = fmaxf(ot[0] * inv, 0.f);
        st.y = fmaxf(ot[1] * inv, 0.f);
        st.z = fmaxf(ot[2] * inv, 0.f);
        st.w = fmaxf(ot[3] * inv, 0.f);
        *(float4*)(&sRed[(w * 64 + 16 * j + c) * OUTC + 4 * g]) = st;
    }

    __syncthreads();

    // block reduce over 4 waves -> plain coalesced partial store (NO atomics)
    {
        int t = tid >> 2, dq = tid & 3;
        const float4 a0 = *(const float4*)(&sRed[(0 * 64 + t) * OUTC + dq * 4]);
        const float4 a1 = *(const float4*)(&sRed[(1 * 64 + t) * OUTC + dq * 4]);
        const float4 a2 = *(const float4*)(&sRed[(2 * 64 + t) * OUTC + dq * 4]);
        const float4 a3 = *(const float4*)(&sRed[(3 * 64 + t) * OUTC + dq * 4]);
        float4 st;
        st.x = a0.x + a1.x + a2.x + a3.x;
        st.y = a0.y + a1.y + a2.y + a3.y;
        st.z = a0.z + a1.z + a2.z + a3.z;
        st.w = a0.w + a1.w + a2.w + a3.w;
        float* wsf = (float*)ws;
        *(float4*)(wsf + WS_PART + (size_t)blockIdx.x * 1024 + t * 16 + dq * 4) = st;
    }
}

// grid: NB blocks; sums NPART partials per output element + MOVE passthrough
__global__ __launch_bounds__(256) void reduce_kernel(
    const float* __restrict__ inp, const float* __restrict__ ws,
    float* __restrict__ out)
{
    const int b   = blockIdx.x;
    const int tid = threadIdx.x;
    const float* pb = ws + WS_PART + (size_t)b * (NPART * 1024);

    if (tid < 64) {
        float4 mv = *(const float4*)(inp + ((size_t)b * NA + tid) * OBS);
        *(float4*)(out + ((size_t)b * NA + tid) * OUTC) = mv;
    }
    int e4 = tid * 4;                 // e = t*16 + d
    float4 s = make_float4(0.f, 0.f, 0.f, 0.f);
    #pragma unroll
    for (int p = 0; p < NPART; ++p) {
        const float4 a = *(const float4*)(pb + p * 1024 + e4);
        s.x += a.x; s.y += a.y; s.z += a.z; s.w += a.w;
    }
    int t = e4 >> 4, d = e4 & 15;
    *(float4*)(out + ((size_t)b * NA + t) * OUTC + MOVE + d) = s;
}

extern "C" void kernel_launch(void* const* d_in, const int* in_sizes, int n_in,
                              void* d_out, int out_size, void* d_ws, size_t ws_size,
                              hipStream_t stream) {
    const float* inp = (const float*)d_in[0];
    const float* Wq  = (const float*)d_in[1];
    const float* bq  = (const float*)d_in[2];
    const float* Wk  = (const float*)d_in[3];
    const float* bk  = (const float*)d_in[4];
    const float* Wv  = (const float*)d_in[5];
    const float* bv  = (const float*)d_in[6];
    const float* Wo  = (const float*)d_in[7];
    const float* bo  = (const float*)d_in[8];
    float* out = (float*)d_out;
    float* ws  = (float*)d_ws;

    hipLaunchKernelGGL(prep_kernel, dim3(1), dim3(256), 0, stream,
                       Wq, bq, Wk, bk, Wv, bv, Wo, bo, ws);
    hipLaunchKernelGGL(attn_kernel, dim3(NTASK / WPB), dim3(256), 0, stream, inp, ws);
    hipLaunchKernelGGL(reduce_kernel, dim3(NB), dim3(256), 0, stream, inp, ws, out);
}

// Round 13
// 44.229 us; speedup vs baseline: 1.1328x; 1.0088x over previous
//
#include <hip/hip_runtime.h>

#define NA 64
#define MOVE 4
#define OBS 5124
#define ROWS 80        // dyn inner row stride (elements)
#define NB 256
#define NTASK (NB * NA)   // 16384 (b,i) tasks
#define OUTC 20
#define WPB 4             // waves per block (1 task per wave)
#define NPART 16          // blocks per batch element

// ws layout: bf16x8 frag tables [0..191] (bf16x8 units, biases folded in k-slot 16),
// partials at float offset WS_PART: [4096 blocks][1024] floats (16.8 MB)
#define WS_WQ 0
#define WS_WK 64
#define WS_WV 128
#define WS_PART 1024

typedef __attribute__((ext_vector_type(8))) short bf16x8;
typedef __attribute__((ext_vector_type(4))) float f32x4;

__device__ __forceinline__ short f2bf(float f) {
    __bf16 h = (__bf16)f;
    return __builtin_bit_cast(short, h);
}
__device__ __forceinline__ bf16x8 pack4(f32x4 v) {
    bf16x8 t;
    t[0] = f2bf(v[0]); t[1] = f2bf(v[1]); t[2] = f2bf(v[2]); t[3] = f2bf(v[3]);
    t[4] = 0; t[5] = 0; t[6] = 0; t[7] = 0;
    return t;
}
__device__ __forceinline__ bf16x8 pack8(f32x4 lo, f32x4 hi) {
    bf16x8 t;
    t[0] = f2bf(lo[0]); t[1] = f2bf(lo[1]); t[2] = f2bf(lo[2]); t[3] = f2bf(lo[3]);
    t[4] = f2bf(hi[0]); t[5] = f2bf(hi[1]); t[6] = f2bf(hi[2]); t[7] = f2bf(hi[3]);
    return t;
}
// dyn fragment: slots 0-3 = data, slot 4 = 1.0 on g==0 lanes (bias activation, k=16)
__device__ __forceinline__ bf16x8 dyfrag(f32x4 v, short s4) {
    bf16x8 t;
    t[0] = f2bf(v[0]); t[1] = f2bf(v[1]); t[2] = f2bf(v[2]); t[3] = f2bf(v[3]);
    t[4] = s4; t[5] = 0; t[6] = 0; t[7] = 0;
    return t;
}

__global__ __launch_bounds__(256) void prep_kernel(
    const float* __restrict__ Wq, const float* __restrict__ bq,
    const float* __restrict__ Wk, const float* __restrict__ bk,
    const float* __restrict__ Wv, const float* __restrict__ bv,
    const float* __restrict__ Wo, const float* __restrict__ bo,
    float* __restrict__ ws)
{
    __shared__ float sWvo[256];
    const float SC = 0.36067376022224085f;   // 0.25 * log2(e)
    int tid = threadIdx.x;
    {
        int e = tid >> 4, d = tid & 15;
        float acc = 0.f;
        #pragma unroll
        for (int c = 0; c < 16; ++c) acc += Wv[e * 16 + c] * Wo[c * 16 + d];
        sWvo[e * 16 + d] = acc;
    }
    __syncthreads();
    if (tid < 64) {
        int g = tid >> 4, c = tid & 15;
        bf16x8 q, k, v;
        #pragma unroll
        for (int r = 0; r < 4; ++r) {
            q[r] = f2bf(Wq[(4 * g + r) * 16 + c]);
            k[r] = f2bf(SC * Wk[(4 * g + r) * 16 + c]);
            v[r] = f2bf(sWvo[(4 * g + r) * 16 + c]);
        }
        // k=16 slot (g==0, slot 4) carries the bias row/col; zero-bias here so exact
        float bvo_c = bo[c];
        #pragma unroll
        for (int e = 0; e < 16; ++e) bvo_c += bv[e] * Wo[e * 16 + c];
        q[4] = (g == 0) ? f2bf(bq[c]) : (short)0;
        k[4] = (g == 0) ? f2bf(SC * bk[c]) : (short)0;
        v[4] = (g == 0) ? f2bf(bvo_c) : (short)0;
        q[5] = q[6] = q[7] = 0;
        k[5] = k[6] = k[7] = 0;
        v[5] = v[6] = v[7] = 0;
        ((bf16x8*)ws)[WS_WQ + tid] = q;
        ((bf16x8*)ws)[WS_WK + tid] = k;
        ((bf16x8*)ws)[WS_WV + tid] = v;
    }
}

// grid: NTASK/WPB = 4096 blocks of 256; wave w handles task idx = blockIdx*4 + w
__global__ __launch_bounds__(256, 8) void attn_kernel(
    const float* __restrict__ inp,
    const float* __restrict__ ws_ro,
    float* __restrict__ ws)
{
    __shared__ float sRed[WPB * 64 * OUTC];   // 20 KiB

    const int tid  = threadIdx.x;
    const int lane = tid & 63;
    const int w    = tid >> 6;
    const int idx  = blockIdx.x * WPB + w;    // b*NA + i
    const int g    = lane >> 4;
    const int c    = lane & 15;

    const bf16x8 wq = ((const bf16x8*)ws_ro)[WS_WQ + lane];
    const bf16x8 wk = ((const bf16x8*)ws_ro)[WS_WK + lane];
    const bf16x8 wv = ((const bf16x8*)ws_ro)[WS_WV + lane];
    const short s4 = (g == 0) ? (short)0x3f80 : (short)0;   // bf16 1.0

    // dyn loads issued up-front (4 x dwordx4, stride 5120 B)
    const float* dynp = inp + (size_t)idx * OBS + MOVE + (size_t)c * ROWS + 4 * g;
    f32x4 f0 = *(const f32x4*)(dynp + 0 * 16 * ROWS);
    f32x4 f1 = *(const f32x4*)(dynp + 1 * 16 * ROWS);
    f32x4 f2 = *(const f32x4*)(dynp + 2 * 16 * ROWS);
    f32x4 f3 = *(const f32x4*)(dynp + 3 * 16 * ROWS);

    const f32x4 zc = {0.f, 0.f, 0.f, 0.f};

    // projections consumed per-i (dy fragments die early; biases via k=16 slot)
    bf16x8 qb[4], kb[4], vb_lo, vb_hi;
    {
        bf16x8 d0 = dyfrag(f0, s4);
        qb[0] = pack4(__builtin_amdgcn_mfma_f32_16x16x32_bf16(wq, d0, zc, 0, 0, 0));
        kb[0] = pack4(__builtin_amdgcn_mfma_f32_16x16x32_bf16(wk, d0, zc, 0, 0, 0));
        f32x4 v0 = __builtin_amdgcn_mfma_f32_16x16x32_bf16(d0, wv, zc, 0, 0, 0);
        bf16x8 d1 = dyfrag(f1, s4);
        qb[1] = pack4(__builtin_amdgcn_mfma_f32_16x16x32_bf16(wq, d1, zc, 0, 0, 0));
        kb[1] = pack4(__builtin_amdgcn_mfma_f32_16x16x32_bf16(wk, d1, zc, 0, 0, 0));
        f32x4 v1 = __builtin_amdgcn_mfma_f32_16x16x32_bf16(d1, wv, zc, 0, 0, 0);
        vb_lo = pack8(v0, v1);
        bf16x8 d2 = dyfrag(f2, s4);
        qb[2] = pack4(__builtin_amdgcn_mfma_f32_16x16x32_bf16(wq, d2, zc, 0, 0, 0));
        kb[2] = pack4(__builtin_amdgcn_mfma_f32_16x16x32_bf16(wk, d2, zc, 0, 0, 0));
        f32x4 v2 = __builtin_amdgcn_mfma_f32_16x16x32_bf16(d2, wv, zc, 0, 0, 0);
        bf16x8 d3 = dyfrag(f3, s4);
        qb[3] = pack4(__builtin_amdgcn_mfma_f32_16x16x32_bf16(wq, d3, zc, 0, 0, 0));
        kb[3] = pack4(__builtin_amdgcn_mfma_f32_16x16x32_bf16(wk, d3, zc, 0, 0, 0));
        f32x4 v3 = __builtin_amdgcn_mfma_f32_16x16x32_bf16(d3, wv, zc, 0, 0, 0);
        vb_hi = pack8(v2, v3);
    }

    // per t-tile j: S^T, streaming no-max softmax (exp2, scale folded), packed PV
    #pragma unroll
    for (int j = 0; j < 4; ++j) {
        f32x4 s0 = __builtin_amdgcn_mfma_f32_16x16x32_bf16(kb[0], qb[j], zc, 0, 0, 0);
        f32x4 s1 = __builtin_amdgcn_mfma_f32_16x16x32_bf16(kb[1], qb[j], zc, 0, 0, 0);
        f32x4 s2 = __builtin_amdgcn_mfma_f32_16x16x32_bf16(kb[2], qb[j], zc, 0, 0, 0);
        f32x4 s3 = __builtin_amdgcn_mfma_f32_16x16x32_bf16(kb[3], qb[j], zc, 0, 0, 0);

        float part = 0.f;
        #pragma unroll
        for (int r = 0; r < 4; ++r) {
            s0[r] = __builtin_amdgcn_exp2f(s0[r]); part += s0[r];
            s1[r] = __builtin_amdgcn_exp2f(s1[r]); part += s1[r];
            s2[r] = __builtin_amdgcn_exp2f(s2[r]); part += s2[r];
            s3[r] = __builtin_amdgcn_exp2f(s3[r]); part += s3[r];
        }
        part += __shfl_xor(part, 16);
        part += __shfl_xor(part, 32);
        float inv = __builtin_amdgcn_rcpf(part);

        bf16x8 p_lo = pack8(s0, s1);
        bf16x8 p_hi = pack8(s2, s3);

        f32x4 ot;
        ot = __builtin_amdgcn_mfma_f32_16x16x32_bf16(vb_lo, p_lo, zc, 0, 0, 0);
        ot = __builtin_amdgcn_mfma_f32_16x16x32_bf16(vb_hi, p_hi, ot, 0, 0, 0);

        // normalize + relu (bvo already folded into V'): stage to LDS
        float4 st;
        st.x = fmaxf(ot[0] * inv, 0.f);
        st.y = fmaxf(ot[1] * inv, 0.f);
        st.z = fmaxf(ot[2] * inv, 0.f);
        st.w = fmaxf(ot[3] * inv, 0.f);
        *(float4*)(&sRed[(w * 64 + 16 * j + c) * OUTC + 4 * g]) = st;
    }

    __syncthreads();

    // block reduce over 4 waves -> plain coalesced partial store (NO atomics)
    {
        int t = tid >> 2, dq = tid & 3;
        const float4 a0 = *(const float4*)(&sRed[(0 * 64 + t) * OUTC + dq * 4]);
        const float4 a1 = *(const float4*)(&sRed[(1 * 64 + t) * OUTC + dq * 4]);
        const float4 a2 = *(const float4*)(&sRed[(2 * 64 + t) * OUTC + dq * 4]);
        const float4 a3 = *(const float4*)(&sRed[(3 * 64 + t) * OUTC + dq * 4]);
        float4 st;
        st.x = a0.x + a1.x + a2.x + a3.x;
        st.y = a0.y + a1.y + a2.y + a3.y;
        st.z = a0.z + a1.z + a2.z + a3.z;
        st.w = a0.w + a1.w + a2.w + a3.w;
        *(float4*)(ws + WS_PART + (size_t)blockIdx.x * 1024 + t * 16 + dq * 4) = st;
    }
}

// grid: NB blocks; sums NPART partials per output element + MOVE passthrough
__global__ __launch_bounds__(256) void reduce_kernel(
    const float* __restrict__ inp, const float* __restrict__ ws,
    float* __restrict__ out)
{
    const int b   = blockIdx.x;
    const int tid = threadIdx.x;
    const float* pb = ws + WS_PART + (size_t)b * (NPART * 1024);

    if (tid < 64) {
        float4 mv = *(const float4*)(inp + ((size_t)b * NA + tid) * OBS);
        *(float4*)(out + ((size_t)b * NA + tid) * OUTC) = mv;
    }
    int e4 = tid * 4;                 // e = t*16 + d
    float4 s = make_float4(0.f, 0.f, 0.f, 0.f);
    #pragma unroll
    for (int p = 0; p < NPART; ++p) {
        const float4 a = *(const float4*)(pb + p * 1024 + e4);
        s.x += a.x; s.y += a.y; s.z += a.z; s.w += a.w;
    }
    int t = e4 >> 4, d = e4 & 15;
    *(float4*)(out + ((size_t)b * NA + t) * OUTC + MOVE + d) = s;
}

extern "C" void kernel_launch(void* const* d_in, const int* in_sizes, int n_in,
                              void* d_out, int out_size, void* d_ws, size_t ws_size,
                              hipStream_t stream) {
    const float* inp = (const float*)d_in[0];
    const float* Wq  = (const float*)d_in[1];
    const float* bq  = (const float*)d_in[2];
    const float* Wk  = (const float*)d_in[3];
    const float* bk  = (const float*)d_in[4];
    const float* Wv  = (const float*)d_in[5];
    const float* bv  = (const float*)d_in[6];
    const float* Wo  = (const float*)d_in[7];
    const float* bo  = (const float*)d_in[8];
    float* out = (float*)d_out;
    float* ws  = (float*)d_ws;

    hipLaunchKernelGGL(prep_kernel, dim3(1), dim3(256), 0, stream,
                       Wq, bq, Wk, bk, Wv, bv, Wo, bo, ws);
    hipLaunchKernelGGL(attn_kernel, dim3(NTASK / WPB), dim3(256), 0, stream, inp, ws, ws);
    hipLaunchKernelGGL(reduce_kernel, dim3(NB), dim3(256), 0, stream, inp, ws, out);
}